// Round 7
// baseline (8668.934 us; speedup 1.0000x reference)
//
#include <hip/hip_runtime.h>

#define T_STEPS 4096
#define HD 512
#define G3HD 1536
#define NCODES 4880
#define NWG 16
#define SENT 0xFFFFFFFFu

typedef __attribute__((ext_vector_type(2))) float v2f;
typedef __attribute__((ext_vector_type(4))) unsigned uint4v;

// ---------------------------------------------------------------------------
// GEMM1: visit[4096][512] = H^T (4096x4880) @ X_emb (4880x512)
// ---------------------------------------------------------------------------
__global__ __launch_bounds__(256) void gemm1_kernel(const float* __restrict__ H,
                                                    const float* __restrict__ X,
                                                    float* __restrict__ C) {
  __shared__ float As[16][68];
  __shared__ float Bs[16][68];
  const int m0 = blockIdx.x * 64;
  const int n0 = blockIdx.y * 64;
  const int tid = threadIdx.x;
  const int lk = tid >> 4;
  const int lm = (tid & 15) << 2;
  const int tm = (tid & 15) << 2;
  const int tn = (tid >> 4) << 2;
  float acc[4][4] = {};
  for (int k0 = 0; k0 < NCODES; k0 += 16) {
    float4 av = *(const float4*)(H + (size_t)(k0 + lk) * T_STEPS + m0 + lm);
    float4 bv = *(const float4*)(X + (size_t)(k0 + lk) * HD + n0 + lm);
    __syncthreads();
    *(float4*)(&As[lk][lm]) = av;
    *(float4*)(&Bs[lk][lm]) = bv;
    __syncthreads();
#pragma unroll
    for (int kk = 0; kk < 16; ++kk) {
      float4 a = *(const float4*)(&As[kk][tm]);
      float4 b = *(const float4*)(&Bs[kk][tn]);
      float ar[4] = {a.x, a.y, a.z, a.w};
      float br[4] = {b.x, b.y, b.z, b.w};
#pragma unroll
      for (int i = 0; i < 4; ++i)
#pragma unroll
        for (int j = 0; j < 4; ++j) acc[i][j] += ar[i] * br[j];
    }
  }
#pragma unroll
  for (int i = 0; i < 4; ++i) {
    float4 o = make_float4(acc[i][0], acc[i][1], acc[i][2], acc[i][3]);
    *(float4*)(C + (size_t)(m0 + tm + i) * HD + n0 + tn) = o;
  }
}

// ---------------------------------------------------------------------------
// GEMM2: gi[4096][1536] = visit (4096x512) @ W_ih^T (512x1536) + b_ih
// ---------------------------------------------------------------------------
__global__ __launch_bounds__(256) void gemm2_kernel(const float* __restrict__ A,
                                                    const float* __restrict__ B,
                                                    const float* __restrict__ bias,
                                                    float* __restrict__ Cout) {
  __shared__ float As[16][68];
  __shared__ float Bs[16][68];
  const int m0 = blockIdx.x * 64;
  const int n0 = blockIdx.y * 64;
  const int tid = threadIdx.x;
  const int lr = tid >> 2;
  const int lkq = (tid & 3) << 2;
  const int tm = (tid & 15) << 2;
  const int tn = (tid >> 4) << 2;
  float acc[4][4] = {};
  for (int k0 = 0; k0 < HD; k0 += 16) {
    float4 av = *(const float4*)(A + (size_t)(m0 + lr) * HD + k0 + lkq);
    float4 bv = *(const float4*)(B + (size_t)(n0 + lr) * HD + k0 + lkq);
    __syncthreads();
    As[lkq + 0][lr] = av.x; As[lkq + 1][lr] = av.y;
    As[lkq + 2][lr] = av.z; As[lkq + 3][lr] = av.w;
    Bs[lkq + 0][lr] = bv.x; Bs[lkq + 1][lr] = bv.y;
    Bs[lkq + 2][lr] = bv.z; Bs[lkq + 3][lr] = bv.w;
    __syncthreads();
#pragma unroll
    for (int kk = 0; kk < 16; ++kk) {
      float4 a = *(const float4*)(&As[kk][tm]);
      float4 b = *(const float4*)(&Bs[kk][tn]);
      float ar[4] = {a.x, a.y, a.z, a.w};
      float br[4] = {b.x, b.y, b.z, b.w};
#pragma unroll
      for (int i = 0; i < 4; ++i)
#pragma unroll
        for (int j = 0; j < 4; ++j) acc[i][j] += ar[i] * br[j];
    }
  }
  const float b0 = bias[n0 + tn + 0];
  const float b1 = bias[n0 + tn + 1];
  const float b2 = bias[n0 + tn + 2];
  const float b3 = bias[n0 + tn + 3];
#pragma unroll
  for (int i = 0; i < 4; ++i) {
    float4 o = make_float4(acc[i][0] + b0, acc[i][1] + b1, acc[i][2] + b2, acc[i][3] + b3);
    *(float4*)(Cout + (size_t)(m0 + tm + i) * G3HD + n0 + tn) = o;
  }
}

// ---------------------------------------------------------------------------
// Persistent GRU scan. XCD-pinned team of 16 WGs x 512 thr. Transport is the
// round-5-proven protocol (per-thread 1-dword relaxed-agent poll + sentinel,
// relaxed-agent store, NO fences). Round-6 change: compute-tail surgery.
//   * ONE barrier/step: hT double-buffered (WAR-safe across a single barrier).
//   * Wave-local reduce: wave w owns elements [4w,4w+4); lane (j=lane>>4,
//     kk=lane&15) computes rows {e,512+e,1024+e}, e=32g+4w+j, k in
//     [32kk,32kk+32). k-reduce = 4 shfl_xor levels (1,2,4,8) -- no part LDS,
//     no second barrier, no 24-add partial sum.
//   * Gates + h-store on 4 lanes of EVERY wave (8-way parallel tail, store
//     issues earlier -> shortens the producer->consumer chain).
//   * LDS conflict fix: 16 distinct k-chunks/wave would be 16-way conflict;
//     read-side rotation (lane kk reads pair slot (s+kk)&15, weights loaded
//     in matching rotated order) covers all 32 banks exactly once per s.
// gi bulk-staged to LDS 64 steps ahead (double-buffered); logits downstream.
// (Resubmission of round 6 -- container infra failure, kernel unchanged.)
// ---------------------------------------------------------------------------
__global__ __launch_bounds__(512, 1) void scan_kernel(const float* __restrict__ gi,
                                                      const float* __restrict__ W_hh,
                                                      const float* __restrict__ b_hh,
                                                      float* __restrict__ hs,
                                                      int* __restrict__ ctrl) {
  __shared__ int s_role;
  __shared__ __align__(16) float gibuf[2][64][96];  // [buf][step&63][gate*32+elem]
  __shared__ __align__(16) float hT[2][HD];         // double-buffered h[t-1]
  const int tid = threadIdx.x;

  if (tid == 0) {
    int xcd;
    asm volatile("s_getreg_b32 %0, hwreg(HW_REG_XCC_ID)" : "=s"(xcd));
    int role = -1;
    const int slot = atomicAdd(&ctrl[xcd], 1);
    if (slot < NWG) {
      if (slot == NWG - 1) atomicCAS(&ctrl[8], -1, xcd);
      int wnr;
      while ((wnr = __hip_atomic_load(&ctrl[8], __ATOMIC_RELAXED,
                                      __HIP_MEMORY_SCOPE_AGENT)) < 0) {
        __builtin_amdgcn_s_sleep(16);
      }
      if (wnr == xcd) role = slot;
    }
    s_role = role;
  }
  __syncthreads();
  const int g = s_role;
  if (g < 0) return;

  const int w = tid >> 6;        // wave 0..7 -> elements [4w, 4w+4)
  const int lane = tid & 63;
  const int kk = lane & 15;      // k-16th: k in [32kk, 32kk+32)
  const int j = lane >> 4;       // element-in-wave 0..3
  const int eg = g * 32 + w * 4 + j;  // global element index

  // 96 weight floats per lane, register-resident, loaded in ROTATED pair
  // order: w2[r][s] holds k-pair (s+kk)&15 of this lane's 32-k range.
  v2f w2[3][16];
#pragma unroll
  for (int r = 0; r < 3; ++r) {
    const v2f* wp = (const v2f*)(W_hh + (size_t)(r * HD + eg) * HD + kk * 32);
#pragma unroll
    for (int s = 0; s < 16; ++s) w2[r][s] = wp[(s + kk) & 15];
  }
#pragma unroll
  for (int r = 0; r < 3; ++r)
#pragma unroll
    for (int s = 0; s < 16; ++s) asm volatile("" : "+v"(w2[r][s]));

  const bool is_gate = (kk == 0);
  float bh_r = 0.f, bh_z = 0.f, bh_n = 0.f, hprev = 0.f;
  if (is_gate) {
    bh_r = b_hh[eg];
    bh_z = b_hh[HD + eg];
    bh_n = b_hh[2 * HD + eg];
  }

  unsigned* hs_u = (unsigned*)hs;

  // Prologue: stage gi rows 0..63 into gibuf[0].
  uint4v st[3];
#pragma unroll
  for (int jj = 0; jj < 3; ++jj) {
    const int c = tid + 512 * jj, row = c / 24, seg = c % 24;
    st[jj] = *(const uint4v*)(gi + (size_t)row * G3HD + (seg >> 3) * HD + g * 32 + (seg & 7) * 4);
  }
#pragma unroll
  for (int jj = 0; jj < 3; ++jj) {
    const int c = tid + 512 * jj, row = c / 24, seg = c % 24;
    *(uint4v*)&gibuf[0][row][(seg >> 3) * 32 + (seg & 7) * 4] = st[jj];
  }
  __syncthreads();

  for (int t = 0; t < T_STEPS; ++t) {
    const int pb = t & 1;
    const int cb = (t >> 6) & 1;
    const int ts = t & 63;

    // ---- each thread polls its OWN single dword of h[t-1]: 1 RTT/sweep ----
    if (t == 0) {
      hT[0][tid] = 0.f;  // h(-1) = 0
    } else {
      const unsigned* hp = hs_u + (size_t)(t - 1) * HD + tid;
      unsigned v = __hip_atomic_load(hp, __ATOMIC_RELAXED, __HIP_MEMORY_SCOPE_AGENT);
      while (v == SENT)
        v = __hip_atomic_load(hp, __ATOMIC_RELAXED, __HIP_MEMORY_SCOPE_AGENT);
      hT[pb][tid] = __uint_as_float(v);
    }

    // ---- gi prefetch issue at ts==0 (overlaps barrier + matvec) ----
    if (ts == 0 && t + 64 < T_STEPS) {
#pragma unroll
      for (int jj = 0; jj < 3; ++jj) {
        const int c = tid + 512 * jj, row = c / 24, seg = c % 24;
        st[jj] = *(const uint4v*)(gi + (size_t)(t + 64 + row) * G3HD + (seg >> 3) * HD +
                                 g * 32 + (seg & 7) * 4);
      }
    }
    __syncthreads();  // the only barrier per step: hT[pb] ready

    // ---- gi LDS-write of previously issued block at ts==1 ----
    if (ts == 1 && t + 63 < T_STEPS) {
#pragma unroll
      for (int jj = 0; jj < 3; ++jj) {
        const int c = tid + 512 * jj, row = c / 24, seg = c % 24;
        *(uint4v*)&gibuf[cb ^ 1][row][(seg >> 3) * 32 + (seg & 7) * 4] = st[jj];
      }
    }

    // ---- matvec: 3 rows x 32 k per lane, rotated LDS reads (bank-free) ----
    const v2f* hv = (const v2f*)&hT[pb][kk * 32];
    v2f h2[16];
#pragma unroll
    for (int s = 0; s < 16; ++s) h2[s] = hv[(s + kk) & 15];
    v2f a0 = (v2f)(0.f), a1 = (v2f)(0.f), a2 = (v2f)(0.f);
#pragma unroll
    for (int s = 0; s < 16; ++s) {
      a0 = __builtin_elementwise_fma(w2[0][s], h2[s], a0);
      a1 = __builtin_elementwise_fma(w2[1][s], h2[s], a1);
      a2 = __builtin_elementwise_fma(w2[2][s], h2[s], a2);
    }
    float s0 = a0.x + a0.y;
    float s1 = a1.x + a1.y;
    float s2 = a2.x + a2.y;
#pragma unroll
    for (int mask = 1; mask <= 8; mask <<= 1) {
      s0 += __shfl_xor(s0, mask);
      s1 += __shfl_xor(s1, mask);
      s2 += __shfl_xor(s2, mask);
    }

    // ---- gates on 4 lanes of EVERY wave; single relaxed-agent store ----
    if (is_gate) {
      const int el = w * 4 + j;
      float xr = s0 + gibuf[cb][ts][el] + bh_r;
      float xz = s1 + gibuf[cb][ts][32 + el] + bh_z;
      const float ghn = s2 + bh_n;
      const float gin = gibuf[cb][ts][64 + el];
      const float rr = __builtin_amdgcn_rcpf(1.f + __expf(-xr));
      const float zz = __builtin_amdgcn_rcpf(1.f + __expf(-xz));
      const float y = gin + rr * ghn;
      const float nn = 1.f - 2.f * __builtin_amdgcn_rcpf(__expf(2.f * y) + 1.f);
      const float hnew = nn + zz * (hprev - nn);
      __hip_atomic_store(hs_u + (size_t)t * HD + eg, __float_as_uint(hnew),
                         __ATOMIC_RELAXED, __HIP_MEMORY_SCOPE_AGENT);
      hprev = hnew;
    }
  }
}

// ---------------------------------------------------------------------------
// logits[t] = hs[t] . w_att   (off the scan critical path)
// ---------------------------------------------------------------------------
__global__ __launch_bounds__(256) void logits_kernel(const float* __restrict__ hs,
                                                     const float* __restrict__ w_att,
                                                     float* __restrict__ logits) {
  const int tid = threadIdx.x;
  const int r = blockIdx.x * 32 + (tid >> 3);
  const int c0 = (tid & 7) * 64;
  const float4* hp = (const float4*)(hs + (size_t)r * HD + c0);
  const float4* wp = (const float4*)(w_att + c0);
  float acc = 0.f;
#pragma unroll
  for (int i = 0; i < 16; ++i) {
    float4 h4 = hp[i], w4 = wp[i];
    acc += h4.x * w4.x + h4.y * w4.y + h4.z * w4.z + h4.w * w4.w;
  }
  acc += __shfl_xor(acc, 1);
  acc += __shfl_xor(acc, 2);
  acc += __shfl_xor(acc, 4);
  if ((tid & 7) == 0) logits[r] = acc;
}

// ---------------------------------------------------------------------------
// Softmax over 4096 logits, write alpha; zero out.
// ---------------------------------------------------------------------------
__global__ __launch_bounds__(256) void softmax_kernel(const float* __restrict__ logits,
                                                      float* __restrict__ alpha,
                                                      float* __restrict__ out) {
  __shared__ float tmp[4];
  const int tid = threadIdx.x;
  float l[16];
  float m = -1e30f;
#pragma unroll
  for (int i = 0; i < 16; ++i) {
    l[i] = logits[i * 256 + tid];
    m = fmaxf(m, l[i]);
  }
#pragma unroll
  for (int o = 32; o > 0; o >>= 1) m = fmaxf(m, __shfl_xor(m, o));
  if ((tid & 63) == 0) tmp[tid >> 6] = m;
  __syncthreads();
  m = fmaxf(fmaxf(tmp[0], tmp[1]), fmaxf(tmp[2], tmp[3]));
  __syncthreads();
  float e[16];
  float s = 0.f;
#pragma unroll
  for (int i = 0; i < 16; ++i) {
    e[i] = expf(l[i] - m);
    s += e[i];
  }
#pragma unroll
  for (int o = 32; o > 0; o >>= 1) s += __shfl_xor(s, o);
  if ((tid & 63) == 0) tmp[tid >> 6] = s;
  __syncthreads();
  s = tmp[0] + tmp[1] + tmp[2] + tmp[3];
  const float inv = 1.f / s;
#pragma unroll
  for (int i = 0; i < 16; ++i) alpha[i * 256 + tid] = e[i] * inv;
  out[tid] = 0.f;
  out[256 + tid] = 0.f;
}

// ---------------------------------------------------------------------------
// out[j] = sum_t alpha[t] * hs[t][j].  128 WGs: 2 j-halves x 64 t-chunks.
// ---------------------------------------------------------------------------
__global__ __launch_bounds__(256) void wsum_kernel(const float* __restrict__ alpha,
                                                   const float* __restrict__ hs,
                                                   float* __restrict__ out) {
  const int tid = threadIdx.x;
  const int jblk = (blockIdx.x & 1) * 256;
  const int tc = blockIdx.x >> 1;
  float acc = 0.f;
  for (int tt = 0; tt < 64; ++tt) {
    const int t = tc * 64 + tt;
    acc += alpha[t] * hs[(size_t)t * HD + jblk + tid];
  }
  atomicAdd(&out[jblk + tid], acc);
}

extern "C" void kernel_launch(void* const* d_in, const int* in_sizes, int n_in,
                              void* d_out, int out_size, void* d_ws, size_t ws_size,
                              hipStream_t stream) {
  const float* H     = (const float*)d_in[0];
  // d_in[1] = TE, unused by the reference
  const float* X_emb = (const float*)d_in[2];
  const float* W_ih  = (const float*)d_in[3];
  const float* W_hh  = (const float*)d_in[4];
  const float* b_ih  = (const float*)d_in[5];
  const float* b_hh  = (const float*)d_in[6];
  const float* w_att = (const float*)d_in[7];
  float* out = (float*)d_out;

  char* ws = (char*)d_ws;
  float* visit  = (float*)(ws + 0);          //  8 MB: 4096x512
  float* gi     = (float*)(ws + 8388608);    // 25 MB: 4096x1536
  float* hs     = (float*)(ws + 33554432);   //  8 MB: 4096x512
  float* logits = (float*)(ws + 41943040);   // 16 KB: 4096
  float* alpha  = (float*)(ws + 41959424);   // 16 KB
  int*   ctrl   = (int*)(ws + 41975808);     // [0..7] per-XCD counters, [8] winner

  // sentinel-fill hs (0xFFFFFFFF = -NaN, unreachable from finite GRU math)
  hipMemsetAsync(hs, 0xFF, (size_t)T_STEPS * HD * sizeof(float), stream);
  hipMemsetAsync(ctrl, 0, 8 * sizeof(int), stream);
  hipMemsetAsync(ctrl + 8, 0xFF, sizeof(int), stream);  // winner = -1

  gemm1_kernel<<<dim3(64, 8), 256, 0, stream>>>(H, X_emb, visit);
  gemm2_kernel<<<dim3(64, 24), 256, 0, stream>>>(visit, W_ih, b_ih, gi);
  scan_kernel<<<256, 512, 0, stream>>>(gi, W_hh, b_hh, hs, ctrl);
  logits_kernel<<<128, 256, 0, stream>>>(hs, w_att, logits);
  softmax_kernel<<<1, 256, 0, stream>>>(logits, alpha, out);
  wsum_kernel<<<128, 256, 0, stream>>>(alpha, hs, out);
}

// Round 8
// 5491.774 us; speedup vs baseline: 1.5785x; 1.5785x over previous
//
#include <hip/hip_runtime.h>

#define T_STEPS 4096
#define HD 512
#define G3HD 1536
#define NCODES 4880
#define NWG 16
#define SENT 0xFFFFFFFFu

typedef __attribute__((ext_vector_type(2))) float v2f;
typedef __attribute__((ext_vector_type(4))) unsigned uint4v;

// ---------------------------------------------------------------------------
// GEMM1: visit[4096][512] = H^T (4096x4880) @ X_emb (4880x512)
// ---------------------------------------------------------------------------
__global__ __launch_bounds__(256) void gemm1_kernel(const float* __restrict__ H,
                                                    const float* __restrict__ X,
                                                    float* __restrict__ C) {
  __shared__ float As[16][68];
  __shared__ float Bs[16][68];
  const int m0 = blockIdx.x * 64;
  const int n0 = blockIdx.y * 64;
  const int tid = threadIdx.x;
  const int lk = tid >> 4;
  const int lm = (tid & 15) << 2;
  const int tm = (tid & 15) << 2;
  const int tn = (tid >> 4) << 2;
  float acc[4][4] = {};
  for (int k0 = 0; k0 < NCODES; k0 += 16) {
    float4 av = *(const float4*)(H + (size_t)(k0 + lk) * T_STEPS + m0 + lm);
    float4 bv = *(const float4*)(X + (size_t)(k0 + lk) * HD + n0 + lm);
    __syncthreads();
    *(float4*)(&As[lk][lm]) = av;
    *(float4*)(&Bs[lk][lm]) = bv;
    __syncthreads();
#pragma unroll
    for (int kk = 0; kk < 16; ++kk) {
      float4 a = *(const float4*)(&As[kk][tm]);
      float4 b = *(const float4*)(&Bs[kk][tn]);
      float ar[4] = {a.x, a.y, a.z, a.w};
      float br[4] = {b.x, b.y, b.z, b.w};
#pragma unroll
      for (int i = 0; i < 4; ++i)
#pragma unroll
        for (int j = 0; j < 4; ++j) acc[i][j] += ar[i] * br[j];
    }
  }
#pragma unroll
  for (int i = 0; i < 4; ++i) {
    float4 o = make_float4(acc[i][0], acc[i][1], acc[i][2], acc[i][3]);
    *(float4*)(C + (size_t)(m0 + tm + i) * HD + n0 + tn) = o;
  }
}

// ---------------------------------------------------------------------------
// GEMM2: gi[4096][1536] = visit (4096x512) @ W_ih^T (512x1536) + b_ih
// ---------------------------------------------------------------------------
__global__ __launch_bounds__(256) void gemm2_kernel(const float* __restrict__ A,
                                                    const float* __restrict__ B,
                                                    const float* __restrict__ bias,
                                                    float* __restrict__ Cout) {
  __shared__ float As[16][68];
  __shared__ float Bs[16][68];
  const int m0 = blockIdx.x * 64;
  const int n0 = blockIdx.y * 64;
  const int tid = threadIdx.x;
  const int lr = tid >> 2;
  const int lkq = (tid & 3) << 2;
  const int tm = (tid & 15) << 2;
  const int tn = (tid >> 4) << 2;
  float acc[4][4] = {};
  for (int k0 = 0; k0 < HD; k0 += 16) {
    float4 av = *(const float4*)(A + (size_t)(m0 + lr) * HD + k0 + lkq);
    float4 bv = *(const float4*)(B + (size_t)(n0 + lr) * HD + k0 + lkq);
    __syncthreads();
    As[lkq + 0][lr] = av.x; As[lkq + 1][lr] = av.y;
    As[lkq + 2][lr] = av.z; As[lkq + 3][lr] = av.w;
    Bs[lkq + 0][lr] = bv.x; Bs[lkq + 1][lr] = bv.y;
    Bs[lkq + 2][lr] = bv.z; Bs[lkq + 3][lr] = bv.w;
    __syncthreads();
#pragma unroll
    for (int kk = 0; kk < 16; ++kk) {
      float4 a = *(const float4*)(&As[kk][tm]);
      float4 b = *(const float4*)(&Bs[kk][tn]);
      float ar[4] = {a.x, a.y, a.z, a.w};
      float br[4] = {b.x, b.y, b.z, b.w};
#pragma unroll
      for (int i = 0; i < 4; ++i)
#pragma unroll
        for (int j = 0; j < 4; ++j) acc[i][j] += ar[i] * br[j];
    }
  }
  const float b0 = bias[n0 + tn + 0];
  const float b1 = bias[n0 + tn + 1];
  const float b2 = bias[n0 + tn + 2];
  const float b3 = bias[n0 + tn + 3];
#pragma unroll
  for (int i = 0; i < 4; ++i) {
    float4 o = make_float4(acc[i][0] + b0, acc[i][1] + b1, acc[i][2] + b2, acc[i][3] + b3);
    *(float4*)(Cout + (size_t)(m0 + tm + i) * G3HD + n0 + tn) = o;
  }
}

// ---------------------------------------------------------------------------
// Persistent GRU scan. EXACT round-5 structure (proven 5050 us scan): 16 WGs
// x 512 thr, per-thread 1-dword poll -> hT LDS, B1, 8-wave matvec (3 rows x
// 32k/lane, 48 pk-fma), 1 shfl_xor(32), part LDS, B2, gates+SINGLE-WAVE
// COALESCED 128B store on wave0 lanes<32 (round-6 lesson: never scatter the
// h-store). ONE bounded change: dual-channel transport experiment.
//   producer: sc1 (IF$, proven channel) store FIRST, then plain store (-> L2,
//     same-XCD fast channel). Same dword, both carry the data.
//   consumer: ONE sc0 (L2-scope) sample; on miss fall IMMEDIATELY into the
//     proven relaxed-agent (sc1) loop. Worst case +~200cy/step; best case
//     -~800cy/step if same-XCD L2 transport works. Diagnostic either way.
// ---------------------------------------------------------------------------
__global__ __launch_bounds__(512, 1) void scan_kernel(const float* __restrict__ gi,
                                                      const float* __restrict__ W_hh,
                                                      const float* __restrict__ b_hh,
                                                      float* __restrict__ hs,
                                                      int* __restrict__ ctrl) {
  __shared__ int s_role;
  __shared__ __align__(16) float gibuf[2][64][96];  // [buf][step&63][gate*32+elem]
  __shared__ __align__(16) float hT[HD];            // h[t-1], linear
  __shared__ float part[8][3][32];                  // [wave][gate][elem]
  const int tid = threadIdx.x;

  if (tid == 0) {
    int xcd;
    asm volatile("s_getreg_b32 %0, hwreg(HW_REG_XCC_ID)" : "=s"(xcd));
    int role = -1;
    const int slot = atomicAdd(&ctrl[xcd], 1);
    if (slot < NWG) {
      if (slot == NWG - 1) atomicCAS(&ctrl[8], -1, xcd);
      int wnr;
      while ((wnr = __hip_atomic_load(&ctrl[8], __ATOMIC_RELAXED,
                                      __HIP_MEMORY_SCOPE_AGENT)) < 0) {
        __builtin_amdgcn_s_sleep(16);
      }
      if (wnr == xcd) role = slot;
    }
    s_role = role;
  }
  __syncthreads();
  const int g = s_role;
  if (g < 0) return;

  const int w = tid >> 6;      // wave 0..7 -> k range [64w, 64w+64)
  const int lane = tid & 63;
  const int e2 = lane & 31;    // element-in-WG 0..31
  const int q = lane >> 5;     // k half -> 32-float chunk
  const int k0 = w * 64 + q * 32;

  // 96 weight floats per lane, register-resident across the whole scan.
  v2f w2[3][16];
#pragma unroll
  for (int r = 0; r < 3; ++r) {
    const v2f* wp = (const v2f*)(W_hh + (size_t)(r * HD + g * 32 + e2) * HD + k0);
#pragma unroll
    for (int j = 0; j < 16; ++j) w2[r][j] = wp[j];
  }
#pragma unroll
  for (int r = 0; r < 3; ++r)
#pragma unroll
    for (int j = 0; j < 16; ++j) asm volatile("" : "+v"(w2[r][j]));

  float bh_r = 0.f, bh_z = 0.f, bh_n = 0.f, hprev = 0.f;
  if (tid < 32) {
    const int ej = g * 32 + tid;
    bh_r = b_hh[ej];
    bh_z = b_hh[HD + ej];
    bh_n = b_hh[2 * HD + ej];
  }

  unsigned* hs_u = (unsigned*)hs;

  // Prologue: stage gi rows 0..63 into gibuf[0].
  uint4v st[3];
#pragma unroll
  for (int j = 0; j < 3; ++j) {
    const int c = tid + 512 * j, row = c / 24, seg = c % 24;
    st[j] = *(const uint4v*)(gi + (size_t)row * G3HD + (seg >> 3) * HD + g * 32 + (seg & 7) * 4);
  }
#pragma unroll
  for (int j = 0; j < 3; ++j) {
    const int c = tid + 512 * j, row = c / 24, seg = c % 24;
    *(uint4v*)&gibuf[0][row][(seg >> 3) * 32 + (seg & 7) * 4] = st[j];
  }
  __syncthreads();

  for (int t = 0; t < T_STEPS; ++t) {
    const int cb = (t >> 6) & 1;
    const int ts = t & 63;

    // ---- each thread polls its OWN single dword of h[t-1] ----
    if (t == 0) {
      hT[tid] = 0.f;  // h(-1) = 0
    } else {
      const unsigned* hp = hs_u + (size_t)(t - 1) * HD + tid;
      // fast path: one L2-scope sample (sc0 = bypass L1, served by shared L2)
      unsigned v;
      asm volatile(
          "global_load_dword %0, %1, off sc0\n\t"
          "s_waitcnt vmcnt(0)"
          : "=v"(v)
          : "v"(hp)
          : "memory");
      if (v == SENT) {
        // proven channel: relaxed-agent (IF$) loop
        do {
          v = __hip_atomic_load(hp, __ATOMIC_RELAXED, __HIP_MEMORY_SCOPE_AGENT);
        } while (v == SENT);
      }
      hT[tid] = __uint_as_float(v);
    }
    __syncthreads();  // B1: hT ready

    // ---- matvec: 3 rows x 32 k per lane, 48 v_pk_fma_f32 (broadcast LDS) ----
    const v2f* hv = (const v2f*)&hT[k0];
    v2f h2[16];
#pragma unroll
    for (int m = 0; m < 16; ++m) h2[m] = hv[m];
    v2f a0 = (v2f)(0.f), a1 = (v2f)(0.f), a2 = (v2f)(0.f);
#pragma unroll
    for (int m = 0; m < 16; ++m) {
      a0 = __builtin_elementwise_fma(w2[0][m], h2[m], a0);
      a1 = __builtin_elementwise_fma(w2[1][m], h2[m], a1);
      a2 = __builtin_elementwise_fma(w2[2][m], h2[m], a2);
    }
    float s0 = a0.x + a0.y;
    float s1 = a1.x + a1.y;
    float s2 = a2.x + a2.y;
    s0 += __shfl_xor(s0, 32);
    s1 += __shfl_xor(s1, 32);
    s2 += __shfl_xor(s2, 32);
    if (q == 0) {
      part[w][0][e2] = s0;
      part[w][1][e2] = s1;
      part[w][2][e2] = s2;
    }

    // ---- gi staging: issue next block at ts==0, LDS-write it at ts==1 ----
    if (ts == 0 && t + 64 < T_STEPS) {
#pragma unroll
      for (int j = 0; j < 3; ++j) {
        const int c = tid + 512 * j, row = c / 24, seg = c % 24;
        st[j] = *(const uint4v*)(gi + (size_t)(t + 64 + row) * G3HD + (seg >> 3) * HD +
                                 g * 32 + (seg & 7) * 4);
      }
    }
    if (ts == 1 && t + 63 < T_STEPS) {
#pragma unroll
      for (int j = 0; j < 3; ++j) {
        const int c = tid + 512 * j, row = c / 24, seg = c % 24;
        *(uint4v*)&gibuf[cb ^ 1][row][(seg >> 3) * 32 + (seg & 7) * 4] = st[j];
      }
    }
    __syncthreads();  // B2: partials ready

    // ---- gates on 32 lanes of wave0; dual-channel store (sc1 then plain) ----
    if (tid < 32) {
      float xr = 0.f, xz = 0.f, xn = 0.f;
#pragma unroll
      for (int ww = 0; ww < 8; ++ww) {
        xr += part[ww][0][tid];
        xz += part[ww][1][tid];
        xn += part[ww][2][tid];
      }
      const float gir = gibuf[cb][ts][tid];
      const float giz = gibuf[cb][ts][32 + tid];
      const float gin = gibuf[cb][ts][64 + tid];
      xr += gir + bh_r;
      xz += giz + bh_z;
      const float ghn = xn + bh_n;
      const float rr = __builtin_amdgcn_rcpf(1.f + __expf(-xr));
      const float zz = __builtin_amdgcn_rcpf(1.f + __expf(-xz));
      const float y = gin + rr * ghn;
      const float nn = 1.f - 2.f * __builtin_amdgcn_rcpf(__expf(2.f * y) + 1.f);
      const float hnew = nn + zz * (hprev - nn);
      unsigned* addr = hs_u + (size_t)t * HD + g * 32 + tid;
      const unsigned uval = __float_as_uint(hnew);
      // proven IF$ channel first (keeps fallback latency = round-5), then the
      // plain store -> shared L2 (fast same-XCD channel for the sc0 sample).
      __hip_atomic_store(addr, uval, __ATOMIC_RELAXED, __HIP_MEMORY_SCOPE_AGENT);
      asm volatile("global_store_dword %0, %1, off" ::"v"(addr), "v"(uval) : "memory");
      hprev = hnew;
    }
  }
}

// ---------------------------------------------------------------------------
// logits[t] = hs[t] . w_att   (off the scan critical path)
// ---------------------------------------------------------------------------
__global__ __launch_bounds__(256) void logits_kernel(const float* __restrict__ hs,
                                                     const float* __restrict__ w_att,
                                                     float* __restrict__ logits) {
  const int tid = threadIdx.x;
  const int r = blockIdx.x * 32 + (tid >> 3);
  const int c0 = (tid & 7) * 64;
  const float4* hp = (const float4*)(hs + (size_t)r * HD + c0);
  const float4* wp = (const float4*)(w_att + c0);
  float acc = 0.f;
#pragma unroll
  for (int i = 0; i < 16; ++i) {
    float4 h4 = hp[i], w4 = wp[i];
    acc += h4.x * w4.x + h4.y * w4.y + h4.z * w4.z + h4.w * w4.w;
  }
  acc += __shfl_xor(acc, 1);
  acc += __shfl_xor(acc, 2);
  acc += __shfl_xor(acc, 4);
  if ((tid & 7) == 0) logits[r] = acc;
}

// ---------------------------------------------------------------------------
// Softmax over 4096 logits, write alpha; zero out.
// ---------------------------------------------------------------------------
__global__ __launch_bounds__(256) void softmax_kernel(const float* __restrict__ logits,
                                                      float* __restrict__ alpha,
                                                      float* __restrict__ out) {
  __shared__ float tmp[4];
  const int tid = threadIdx.x;
  float l[16];
  float m = -1e30f;
#pragma unroll
  for (int i = 0; i < 16; ++i) {
    l[i] = logits[i * 256 + tid];
    m = fmaxf(m, l[i]);
  }
#pragma unroll
  for (int o = 32; o > 0; o >>= 1) m = fmaxf(m, __shfl_xor(m, o));
  if ((tid & 63) == 0) tmp[tid >> 6] = m;
  __syncthreads();
  m = fmaxf(fmaxf(tmp[0], tmp[1]), fmaxf(tmp[2], tmp[3]));
  __syncthreads();
  float e[16];
  float s = 0.f;
#pragma unroll
  for (int i = 0; i < 16; ++i) {
    e[i] = expf(l[i] - m);
    s += e[i];
  }
#pragma unroll
  for (int o = 32; o > 0; o >>= 1) s += __shfl_xor(s, o);
  if ((tid & 63) == 0) tmp[tid >> 6] = s;
  __syncthreads();
  s = tmp[0] + tmp[1] + tmp[2] + tmp[3];
  const float inv = 1.f / s;
#pragma unroll
  for (int i = 0; i < 16; ++i) alpha[i * 256 + tid] = e[i] * inv;
  out[tid] = 0.f;
  out[256 + tid] = 0.f;
}

// ---------------------------------------------------------------------------
// out[j] = sum_t alpha[t] * hs[t][j].  128 WGs: 2 j-halves x 64 t-chunks.
// ---------------------------------------------------------------------------
__global__ __launch_bounds__(256) void wsum_kernel(const float* __restrict__ alpha,
                                                   const float* __restrict__ hs,
                                                   float* __restrict__ out) {
  const int tid = threadIdx.x;
  const int jblk = (blockIdx.x & 1) * 256;
  const int tc = blockIdx.x >> 1;
  float acc = 0.f;
  for (int tt = 0; tt < 64; ++tt) {
    const int t = tc * 64 + tt;
    acc += alpha[t] * hs[(size_t)t * HD + jblk + tid];
  }
  atomicAdd(&out[jblk + tid], acc);
}

extern "C" void kernel_launch(void* const* d_in, const int* in_sizes, int n_in,
                              void* d_out, int out_size, void* d_ws, size_t ws_size,
                              hipStream_t stream) {
  const float* H     = (const float*)d_in[0];
  // d_in[1] = TE, unused by the reference
  const float* X_emb = (const float*)d_in[2];
  const float* W_ih  = (const float*)d_in[3];
  const float* W_hh  = (const float*)d_in[4];
  const float* b_ih  = (const float*)d_in[5];
  const float* b_hh  = (const float*)d_in[6];
  const float* w_att = (const float*)d_in[7];
  float* out = (float*)d_out;

  char* ws = (char*)d_ws;
  float* visit  = (float*)(ws + 0);          //  8 MB: 4096x512
  float* gi     = (float*)(ws + 8388608);    // 25 MB: 4096x1536
  float* hs     = (float*)(ws + 33554432);   //  8 MB: 4096x512
  float* logits = (float*)(ws + 41943040);   // 16 KB: 4096
  float* alpha  = (float*)(ws + 41959424);   // 16 KB
  int*   ctrl   = (int*)(ws + 41975808);     // [0..7] per-XCD counters, [8] winner

  // sentinel-fill hs (0xFFFFFFFF = -NaN, unreachable from finite GRU math)
  hipMemsetAsync(hs, 0xFF, (size_t)T_STEPS * HD * sizeof(float), stream);
  hipMemsetAsync(ctrl, 0, 8 * sizeof(int), stream);
  hipMemsetAsync(ctrl + 8, 0xFF, sizeof(int), stream);  // winner = -1

  gemm1_kernel<<<dim3(64, 8), 256, 0, stream>>>(H, X_emb, visit);
  gemm2_kernel<<<dim3(64, 24), 256, 0, stream>>>(visit, W_ih, b_ih, gi);
  scan_kernel<<<256, 512, 0, stream>>>(gi, W_hh, b_hh, hs, ctrl);
  logits_kernel<<<128, 256, 0, stream>>>(hs, w_att, logits);
  softmax_kernel<<<1, 256, 0, stream>>>(logits, alpha, out);
  wsum_kernel<<<128, 256, 0, stream>>>(alpha, hs, out);
}